// Round 1
// baseline (740.767 us; speedup 1.0000x reference)
//
#include <hip/hip_runtime.h>
#include <hip/hip_bf16.h>

// Problem constants (reference: T=8192, H=1024, I=2816, E=8)
#define T_TOK 8192
#define H_DIM 1024
#define I_DIM 2816
#define E_EXP 8

#define BM 128
#define BN 128
#define BK 64
#define MAXTILES (T_TOK / BM + E_EXP) // 72 worst case

typedef __bf16 bf16x8 __attribute__((ext_vector_type(8)));
typedef float f32x4 __attribute__((ext_vector_type(4)));

// swizzled LDS byte offset for a [rows][BK(bf16)] tile; row stride = BK*2 = 128B
#define SWZ(r, bc) (((r) * (BK * 2)) + (((bc) ^ (((r) & 7) << 4))))

__device__ __forceinline__ void cvt_store(unsigned char* sm, int off,
                                          const float4& p0, const float4& p1) {
  bf16x8 v;
  v[0] = (__bf16)p0.x; v[1] = (__bf16)p0.y; v[2] = (__bf16)p0.z; v[3] = (__bf16)p0.w;
  v[4] = (__bf16)p1.x; v[5] = (__bf16)p1.y; v[6] = (__bf16)p1.z; v[7] = (__bf16)p1.w;
  *(bf16x8*)(sm + off) = v;
}

// ---------------- bucketing kernels ----------------
__global__ void k_count(const int* __restrict__ idx, int* __restrict__ counts) {
  int t = blockIdx.x * blockDim.x + threadIdx.x;
  if (t < T_TOK) atomicAdd(&counts[idx[t]], 1);
}

__global__ void k_tiles(const int* __restrict__ counts, int* __restrict__ offsets,
                        int* __restrict__ tE, int* __restrict__ tB,
                        int* __restrict__ tEnd, int* __restrict__ nT) {
  if (threadIdx.x != 0 || blockIdx.x != 0) return;
  int off = 0, nt = 0;
  for (int e = 0; e < E_EXP; ++e) {
    offsets[e] = off;
    int c = counts[e];
    for (int b = 0; b < c; b += BM) { tE[nt] = e; tB[nt] = off + b; tEnd[nt] = off + c; ++nt; }
    off += c;
  }
  offsets[E_EXP] = off;
  *nT = nt;
}

__global__ void k_scatter(const int* __restrict__ idx, const int* __restrict__ offsets,
                          int* __restrict__ cursor, int* __restrict__ order) {
  int t = blockIdx.x * blockDim.x + threadIdx.x;
  if (t < T_TOK) {
    int e = idx[t];
    int p = offsets[e] + atomicAdd(&cursor[e], 1);
    order[p] = t;
  }
}

// ---------------- pass 2: gate/up GEMM + silu*mul -> hp (bf16, permuted rows) ----------------
__global__ __launch_bounds__(256) void k_gateup(
    const float* __restrict__ x, const float* __restrict__ Wg, const float* __restrict__ Wu,
    const int* __restrict__ order, const int* __restrict__ tE, const int* __restrict__ tB,
    const int* __restrict__ tEnd, const int* __restrict__ nT, __bf16* __restrict__ hp) {
  const int tile = blockIdx.y;
  if (tile >= *nT) return;
  const int e = tE[tile];
  const int rowbase = tB[tile];
  const int rowEnd = tEnd[tile];
  const int nbase = blockIdx.x * BN;

  __shared__ __align__(16) unsigned char smA[BM * BK * 2];
  __shared__ __align__(16) unsigned char smG[BN * BK * 2];
  __shared__ __align__(16) unsigned char smU[BN * BK * 2];

  const int tid = threadIdx.x;
  const int lane = tid & 63;
  const int w = tid >> 6;
  const int wm = w >> 1, wn = w & 1;

  // staging role: thread -> (row, half)
  const int r = tid >> 1;
  const int c2 = tid & 1;
  const int gr_s = rowbase + r;
  const bool rvalid = gr_s < rowEnd;
  const float* xrow = rvalid ? (x + (size_t)order[gr_s] * H_DIM) : x;
  const float* grow = Wg + ((size_t)e * I_DIM + nbase + r) * H_DIM;
  const float* urow = Wu + ((size_t)e * I_DIM + nbase + r) * H_DIM;

  f32x4 accg[4][4], accu[4][4];
#pragma unroll
  for (int m = 0; m < 4; ++m)
#pragma unroll
    for (int n = 0; n < 4; ++n)
#pragma unroll
      for (int j = 0; j < 4; ++j) { accg[m][n][j] = 0.f; accu[m][n][j] = 0.f; }

  const int nK = H_DIM / BK; // 16
  for (int kt = 0; kt < nK; ++kt) {
    const int kof = kt * BK + c2 * 32; // f32 col
    // stage A (gathered x rows, f32 -> bf16)
#pragma unroll
    for (int i = 0; i < 4; ++i) {
      const int off = SWZ(r, c2 * 64 + i * 16);
      if (rvalid) {
        const float4 p0 = *(const float4*)(xrow + kof + i * 8);
        const float4 p1 = *(const float4*)(xrow + kof + i * 8 + 4);
        cvt_store(smA, off, p0, p1);
      } else {
        bf16x8 z;
#pragma unroll
        for (int q = 0; q < 8; ++q) z[q] = (__bf16)0.f;
        *(bf16x8*)(smA + off) = z;
      }
    }
    // stage Bg, Bu
#pragma unroll
    for (int i = 0; i < 4; ++i) {
      const int off = SWZ(r, c2 * 64 + i * 16);
      const float4 g0 = *(const float4*)(grow + kof + i * 8);
      const float4 g1 = *(const float4*)(grow + kof + i * 8 + 4);
      cvt_store(smG, off, g0, g1);
      const float4 u0 = *(const float4*)(urow + kof + i * 8);
      const float4 u1 = *(const float4*)(urow + kof + i * 8 + 4);
      cvt_store(smU, off, u0, u1);
    }
    __syncthreads();
#pragma unroll
    for (int ks = 0; ks < 2; ++ks) {
      bf16x8 a[4], bg[4], bu[4];
#pragma unroll
      for (int m = 0; m < 4; ++m) {
        const int row = wm * 64 + m * 16 + (lane & 15);
        a[m] = *(const bf16x8*)(smA + SWZ(row, ks * 64 + ((lane >> 4) * 16)));
      }
#pragma unroll
      for (int n = 0; n < 4; ++n) {
        const int row = wn * 64 + n * 16 + (lane & 15);
        const int off = SWZ(row, ks * 64 + ((lane >> 4) * 16));
        bg[n] = *(const bf16x8*)(smG + off);
        bu[n] = *(const bf16x8*)(smU + off);
      }
#pragma unroll
      for (int m = 0; m < 4; ++m)
#pragma unroll
        for (int n = 0; n < 4; ++n) {
          accg[m][n] = __builtin_amdgcn_mfma_f32_16x16x32_bf16(a[m], bg[n], accg[m][n], 0, 0, 0);
          accu[m][n] = __builtin_amdgcn_mfma_f32_16x16x32_bf16(a[m], bu[n], accu[m][n], 0, 0, 0);
        }
    }
    __syncthreads();
  }

  // epilogue: h = silu(g)*u -> hp (bf16), permuted row layout
#pragma unroll
  for (int m = 0; m < 4; ++m) {
    const int row0 = wm * 64 + m * 16 + (lane >> 4) * 4;
#pragma unroll
    for (int j = 0; j < 4; ++j) {
      const int gr = rowbase + row0 + j;
      if (gr < rowEnd) {
        __bf16* dst = hp + (size_t)gr * I_DIM + nbase;
#pragma unroll
        for (int n = 0; n < 4; ++n) {
          const int col = wn * 64 + n * 16 + (lane & 15);
          const float g = accg[m][n][j];
          const float u = accu[m][n][j];
          const float s = g / (1.f + __expf(-g)) * u;
          dst[col] = (__bf16)s;
        }
      }
    }
  }
}

// ---------------- pass 3: down GEMM, scatter rows to out ----------------
__global__ __launch_bounds__(256) void k_down(
    const __bf16* __restrict__ hp, const float* __restrict__ Wd,
    const int* __restrict__ order, const int* __restrict__ tE, const int* __restrict__ tB,
    const int* __restrict__ tEnd, const int* __restrict__ nT, float* __restrict__ out) {
  const int tile = blockIdx.y;
  if (tile >= *nT) return;
  const int e = tE[tile];
  const int rowbase = tB[tile];
  const int rowEnd = tEnd[tile];
  const int nbase = blockIdx.x * BN; // over H

  __shared__ __align__(16) unsigned char smA[BM * BK * 2];
  __shared__ __align__(16) unsigned char smB[BN * BK * 2];

  const int tid = threadIdx.x;
  const int lane = tid & 63;
  const int w = tid >> 6;
  const int wm = w >> 1, wn = w & 1;

  const int r = tid >> 1;
  const int c2 = tid & 1;
  const __bf16* arow = hp + (size_t)(rowbase + r) * I_DIM; // hp is padded; pad rows read garbage, stores guarded
  const float* brow = Wd + ((size_t)e * H_DIM + nbase + r) * I_DIM;

  f32x4 acc[4][4];
#pragma unroll
  for (int m = 0; m < 4; ++m)
#pragma unroll
    for (int n = 0; n < 4; ++n)
#pragma unroll
      for (int j = 0; j < 4; ++j) acc[m][n][j] = 0.f;

  const int nK = I_DIM / BK; // 44
  for (int kt = 0; kt < nK; ++kt) {
    // stage A (bf16 direct copy)
#pragma unroll
    for (int i = 0; i < 4; ++i) {
      const bf16x8 v = *(const bf16x8*)(arow + kt * BK + c2 * 32 + i * 8);
      *(bf16x8*)(smA + SWZ(r, c2 * 64 + i * 16)) = v;
    }
    // stage B (Wd f32 -> bf16)
    const int kof = kt * BK + c2 * 32;
#pragma unroll
    for (int i = 0; i < 4; ++i) {
      const float4 p0 = *(const float4*)(brow + kof + i * 8);
      const float4 p1 = *(const float4*)(brow + kof + i * 8 + 4);
      cvt_store(smB, SWZ(r, c2 * 64 + i * 16), p0, p1);
    }
    __syncthreads();
#pragma unroll
    for (int ks = 0; ks < 2; ++ks) {
      bf16x8 a[4], b[4];
#pragma unroll
      for (int m = 0; m < 4; ++m) {
        const int row = wm * 64 + m * 16 + (lane & 15);
        a[m] = *(const bf16x8*)(smA + SWZ(row, ks * 64 + ((lane >> 4) * 16)));
      }
#pragma unroll
      for (int n = 0; n < 4; ++n) {
        const int row = wn * 64 + n * 16 + (lane & 15);
        b[n] = *(const bf16x8*)(smB + SWZ(row, ks * 64 + ((lane >> 4) * 16)));
      }
#pragma unroll
      for (int m = 0; m < 4; ++m)
#pragma unroll
        for (int n = 0; n < 4; ++n)
          acc[m][n] = __builtin_amdgcn_mfma_f32_16x16x32_bf16(a[m], b[n], acc[m][n], 0, 0, 0);
    }
    __syncthreads();
  }

  // epilogue: scatter rows to out[token]
#pragma unroll
  for (int m = 0; m < 4; ++m) {
    const int row0 = wm * 64 + m * 16 + (lane >> 4) * 4;
#pragma unroll
    for (int j = 0; j < 4; ++j) {
      const int gr = rowbase + row0 + j;
      if (gr < rowEnd) {
        const int tok = order[gr];
        float* dst = out + (size_t)tok * H_DIM + nbase;
#pragma unroll
        for (int n = 0; n < 4; ++n) {
          const int col = wn * 64 + n * 16 + (lane & 15);
          dst[col] = acc[m][n][j];
        }
      }
    }
  }
}

// ---------------- launch ----------------
extern "C" void kernel_launch(void* const* d_in, const int* in_sizes, int n_in,
                              void* d_out, int out_size, void* d_ws, size_t ws_size,
                              hipStream_t stream) {
  const float* x = (const float*)d_in[0];
  const int* eidx = (const int*)d_in[1];
  const float* Wg = (const float*)d_in[2];
  const float* Wu = (const float*)d_in[3];
  const float* Wd = (const float*)d_in[4];
  float* out = (float*)d_out;

  char* ws = (char*)d_ws;
  size_t off = 0;
  auto alloc = [&](size_t bytes) -> void* {
    void* p = ws + off;
    off = (off + bytes + 255) & ~(size_t)255;
    return p;
  };
  __bf16* hp = (__bf16*)alloc((size_t)(T_TOK + E_EXP * BM) * I_DIM * sizeof(__bf16));
  int* order = (int*)alloc(T_TOK * sizeof(int));
  int* offsets = (int*)alloc((E_EXP + 1) * sizeof(int));
  int* tE = (int*)alloc(MAXTILES * sizeof(int));
  int* tB = (int*)alloc(MAXTILES * sizeof(int));
  int* tEnd = (int*)alloc(MAXTILES * sizeof(int));
  int* nT = (int*)alloc(sizeof(int));
  int* cc = (int*)alloc(2 * E_EXP * sizeof(int)); // counts | cursor
  int* counts = cc;
  int* cursor = cc + E_EXP;

  hipMemsetAsync(cc, 0, 2 * E_EXP * sizeof(int), stream);
  k_count<<<T_TOK / 256, 256, 0, stream>>>(eidx, counts);
  k_tiles<<<1, 1, 0, stream>>>(counts, offsets, tE, tB, tEnd, nT);
  k_scatter<<<T_TOK / 256, 256, 0, stream>>>(eidx, offsets, cursor, order);
  k_gateup<<<dim3(I_DIM / BN, MAXTILES), 256, 0, stream>>>(x, Wg, Wu, order, tE, tB, tEnd, nT, hp);
  k_down<<<dim3(H_DIM / BN, MAXTILES), 256, 0, stream>>>(hp, Wd, order, tE, tB, tEnd, nT, out);
}

// Round 2
// 441.353 us; speedup vs baseline: 1.6784x; 1.6784x over previous
//
#include <hip/hip_runtime.h>
#include <hip/hip_bf16.h>

// Problem constants (reference: T=8192, H=1024, I=2816, E=8)
#define T_TOK 8192
#define H_DIM 1024
#define I_DIM 2816
#define E_EXP 8

#define BM 128
#define BN 128
#define BK 64
#define MAXTILES (T_TOK / BM + E_EXP) // 72 worst case

typedef __bf16 bf16x8 __attribute__((ext_vector_type(8)));
typedef float f32x4 __attribute__((ext_vector_type(4)));

// swizzled LDS byte offset for a [rows][BK(bf16)] tile; row stride = BK*2 = 128B
#define SWZ(r, bc) (((r) * (BK * 2)) + (((bc) ^ (((r) & 7) << 4))))

__device__ __forceinline__ void gload16(const void* g, void* l) {
  __builtin_amdgcn_global_load_lds((const __attribute__((address_space(1))) void*)g,
                                   (__attribute__((address_space(3))) void*)l, 16, 0, 0);
}

__device__ __forceinline__ void cvt_store(unsigned char* sm, int off,
                                          const float4& p0, const float4& p1) {
  bf16x8 v;
  v[0] = (__bf16)p0.x; v[1] = (__bf16)p0.y; v[2] = (__bf16)p0.z; v[3] = (__bf16)p0.w;
  v[4] = (__bf16)p1.x; v[5] = (__bf16)p1.y; v[6] = (__bf16)p1.z; v[7] = (__bf16)p1.w;
  *(bf16x8*)(sm + off) = v;
}

__device__ __forceinline__ bf16x8 cvt8(const float4& p0, const float4& p1) {
  bf16x8 v;
  v[0] = (__bf16)p0.x; v[1] = (__bf16)p0.y; v[2] = (__bf16)p0.z; v[3] = (__bf16)p0.w;
  v[4] = (__bf16)p1.x; v[5] = (__bf16)p1.y; v[6] = (__bf16)p1.z; v[7] = (__bf16)p1.w;
  return v;
}

// ---------------- bucketing kernels ----------------
__global__ void k_count(const int* __restrict__ idx, int* __restrict__ counts) {
  int t = blockIdx.x * blockDim.x + threadIdx.x;
  if (t < T_TOK) atomicAdd(&counts[idx[t]], 1);
}

__global__ void k_tiles(const int* __restrict__ counts, int* __restrict__ offsets,
                        int* __restrict__ tE, int* __restrict__ tB,
                        int* __restrict__ tEnd, int* __restrict__ nT) {
  if (threadIdx.x != 0 || blockIdx.x != 0) return;
  int off = 0, nt = 0;
  for (int e = 0; e < E_EXP; ++e) {
    offsets[e] = off;
    int c = counts[e];
    for (int b = 0; b < c; b += BM) { tE[nt] = e; tB[nt] = off + b; tEnd[nt] = off + c; ++nt; }
    off += c;
  }
  offsets[E_EXP] = off;
  *nT = nt;
}

__global__ void k_scatter(const int* __restrict__ idx, const int* __restrict__ offsets,
                          int* __restrict__ cursor, int* __restrict__ order) {
  int t = blockIdx.x * blockDim.x + threadIdx.x;
  if (t < T_TOK) {
    int e = idx[t];
    int p = offsets[e] + atomicAdd(&cursor[e], 1);
    order[p] = t;
  }
}

// ---------------- bf16 pre-conversion ----------------
__global__ __launch_bounds__(256) void k_cvt(const float* __restrict__ src,
                                             __bf16* __restrict__ dst, int n8) {
  int i = blockIdx.x * blockDim.x + threadIdx.x;
  if (i < n8) {
    const float4 p0 = ((const float4*)src)[i * 2];
    const float4 p1 = ((const float4*)src)[i * 2 + 1];
    ((bf16x8*)dst)[i] = cvt8(p0, p1);
  }
}

// gather by order + convert x -> xp (bf16, permuted rows)
__global__ __launch_bounds__(128) void k_xperm(const float* __restrict__ x,
                                               const int* __restrict__ order,
                                               __bf16* __restrict__ xp) {
  const int row = blockIdx.x;
  const int tok = order[row];
  const float* s = x + (size_t)tok * H_DIM + threadIdx.x * 8;
  const float4 p0 = ((const float4*)s)[0];
  const float4 p1 = ((const float4*)s)[1];
  *(bf16x8*)(xp + (size_t)row * H_DIM + threadIdx.x * 8) = cvt8(p0, p1);
}

// ---------------- pass 2 (bf16 path): gate/up GEMM + silu*mul -> hp ----------------
__global__ __launch_bounds__(256) void k_gateup2(
    const __bf16* __restrict__ xp, const __bf16* __restrict__ wg, const __bf16* __restrict__ wu,
    const int* __restrict__ tE, const int* __restrict__ tB,
    const int* __restrict__ tEnd, const int* __restrict__ nT, __bf16* __restrict__ hp) {
  const int tile = blockIdx.y;
  if (tile >= *nT) return;
  const int e = tE[tile];
  const int rowbase = tB[tile];
  const int rowEnd = tEnd[tile];
  const int nbase = blockIdx.x * BN;

  __shared__ __align__(16) unsigned char smA[BM * BK * 2];
  __shared__ __align__(16) unsigned char smG[BN * BK * 2];
  __shared__ __align__(16) unsigned char smU[BN * BK * 2];

  const int tid = threadIdx.x;
  const int lane = tid & 63;
  const int w = tid >> 6;
  const int wm = w >> 1, wn = w & 1;

  // staging geometry: wave w, call j covers 8 rows starting at (w*4+j)*8;
  // lane l -> local row (l>>3), source chunk (l&7)^(l>>3)  (XOR-swizzle pre-applied
  // on the GLOBAL side; LDS dest stays linear -> ds_read uses SWZ()).
  const int lrow = lane >> 3;
  const int lchunk = (lane & 7) ^ lrow; // 16B chunk index = 8 bf16
  const __bf16* aptr[4];
  const __bf16* gptr[4];
  const __bf16* uptr[4];
#pragma unroll
  for (int j = 0; j < 4; ++j) {
    const int rl = (w * 4 + j) * 8 + lrow;
    aptr[j] = xp + (size_t)(rowbase + rl) * H_DIM + lchunk * 8;
    gptr[j] = wg + ((size_t)e * I_DIM + nbase + rl) * H_DIM + lchunk * 8;
    uptr[j] = wu + ((size_t)e * I_DIM + nbase + rl) * H_DIM + lchunk * 8;
  }

  f32x4 accg[4][4], accu[4][4];
#pragma unroll
  for (int m = 0; m < 4; ++m)
#pragma unroll
    for (int n = 0; n < 4; ++n)
#pragma unroll
      for (int j = 0; j < 4; ++j) { accg[m][n][j] = 0.f; accu[m][n][j] = 0.f; }

  const int nK = H_DIM / BK; // 16
  for (int kt = 0; kt < nK; ++kt) {
    const int kof = kt * BK;
#pragma unroll
    for (int j = 0; j < 4; ++j) {
      unsigned char* lbase = (unsigned char*)smA + (w * 4 + j) * 1024;
      gload16(aptr[j] + kof, lbase);
      gload16(gptr[j] + kof, (unsigned char*)smG + (w * 4 + j) * 1024);
      gload16(uptr[j] + kof, (unsigned char*)smU + (w * 4 + j) * 1024);
    }
    __syncthreads();
#pragma unroll
    for (int ks = 0; ks < 2; ++ks) {
      bf16x8 a[4], bg[4], bu[4];
#pragma unroll
      for (int m = 0; m < 4; ++m) {
        const int row = wm * 64 + m * 16 + (lane & 15);
        a[m] = *(const bf16x8*)(smA + SWZ(row, ks * 64 + ((lane >> 4) * 16)));
      }
#pragma unroll
      for (int n = 0; n < 4; ++n) {
        const int row = wn * 64 + n * 16 + (lane & 15);
        const int off = SWZ(row, ks * 64 + ((lane >> 4) * 16));
        bg[n] = *(const bf16x8*)(smG + off);
        bu[n] = *(const bf16x8*)(smU + off);
      }
#pragma unroll
      for (int m = 0; m < 4; ++m)
#pragma unroll
        for (int n = 0; n < 4; ++n) {
          accg[m][n] = __builtin_amdgcn_mfma_f32_16x16x32_bf16(a[m], bg[n], accg[m][n], 0, 0, 0);
          accu[m][n] = __builtin_amdgcn_mfma_f32_16x16x32_bf16(a[m], bu[n], accu[m][n], 0, 0, 0);
        }
    }
    __syncthreads();
  }

  // epilogue: h = silu(g)*u -> hp (bf16, permuted row layout)
#pragma unroll
  for (int m = 0; m < 4; ++m) {
    const int row0 = wm * 64 + m * 16 + (lane >> 4) * 4;
#pragma unroll
    for (int j = 0; j < 4; ++j) {
      const int gr = rowbase + row0 + j;
      if (gr < rowEnd) {
        __bf16* dst = hp + (size_t)gr * I_DIM + nbase;
#pragma unroll
        for (int n = 0; n < 4; ++n) {
          const int col = wn * 64 + n * 16 + (lane & 15);
          const float g = accg[m][n][j];
          const float u = accu[m][n][j];
          dst[col] = (__bf16)(g / (1.f + __expf(-g)) * u);
        }
      }
    }
  }
}

// ---------------- pass 3 (bf16 path): down GEMM, scatter rows to out ----------------
__global__ __launch_bounds__(256) void k_down2(
    const __bf16* __restrict__ hp, const __bf16* __restrict__ wd,
    const int* __restrict__ order, const int* __restrict__ tE, const int* __restrict__ tB,
    const int* __restrict__ tEnd, const int* __restrict__ nT, float* __restrict__ out) {
  const int tile = blockIdx.y;
  if (tile >= *nT) return;
  const int e = tE[tile];
  const int rowbase = tB[tile];
  const int rowEnd = tEnd[tile];
  const int nbase = blockIdx.x * BN; // over H

  __shared__ __align__(16) unsigned char smA[BM * BK * 2];
  __shared__ __align__(16) unsigned char smB[BN * BK * 2];

  const int tid = threadIdx.x;
  const int lane = tid & 63;
  const int w = tid >> 6;
  const int wm = w >> 1, wn = w & 1;

  const int lrow = lane >> 3;
  const int lchunk = (lane & 7) ^ lrow;
  const __bf16* aptr[4];
  const __bf16* bptr[4];
#pragma unroll
  for (int j = 0; j < 4; ++j) {
    const int rl = (w * 4 + j) * 8 + lrow;
    aptr[j] = hp + (size_t)(rowbase + rl) * I_DIM + lchunk * 8;
    bptr[j] = wd + ((size_t)e * H_DIM + nbase + rl) * I_DIM + lchunk * 8;
  }

  f32x4 acc[4][4];
#pragma unroll
  for (int m = 0; m < 4; ++m)
#pragma unroll
    for (int n = 0; n < 4; ++n)
#pragma unroll
      for (int j = 0; j < 4; ++j) acc[m][n][j] = 0.f;

  const int nK = I_DIM / BK; // 44
  for (int kt = 0; kt < nK; ++kt) {
    const int kof = kt * BK;
#pragma unroll
    for (int j = 0; j < 4; ++j) {
      gload16(aptr[j] + kof, (unsigned char*)smA + (w * 4 + j) * 1024);
      gload16(bptr[j] + kof, (unsigned char*)smB + (w * 4 + j) * 1024);
    }
    __syncthreads();
#pragma unroll
    for (int ks = 0; ks < 2; ++ks) {
      bf16x8 a[4], b[4];
#pragma unroll
      for (int m = 0; m < 4; ++m) {
        const int row = wm * 64 + m * 16 + (lane & 15);
        a[m] = *(const bf16x8*)(smA + SWZ(row, ks * 64 + ((lane >> 4) * 16)));
      }
#pragma unroll
      for (int n = 0; n < 4; ++n) {
        const int row = wn * 64 + n * 16 + (lane & 15);
        b[n] = *(const bf16x8*)(smB + SWZ(row, ks * 64 + ((lane >> 4) * 16)));
      }
#pragma unroll
      for (int m = 0; m < 4; ++m)
#pragma unroll
        for (int n = 0; n < 4; ++n)
          acc[m][n] = __builtin_amdgcn_mfma_f32_16x16x32_bf16(a[m], b[n], acc[m][n], 0, 0, 0);
    }
    __syncthreads();
  }

#pragma unroll
  for (int m = 0; m < 4; ++m) {
    const int row0 = wm * 64 + m * 16 + (lane >> 4) * 4;
#pragma unroll
    for (int j = 0; j < 4; ++j) {
      const int gr = rowbase + row0 + j;
      if (gr < rowEnd) {
        const int tok = order[gr];
        float* dst = out + (size_t)tok * H_DIM + nbase;
#pragma unroll
        for (int n = 0; n < 4; ++n) {
          const int col = wn * 64 + n * 16 + (lane & 15);
          dst[col] = acc[m][n][j];
        }
      }
    }
  }
}

// ---------------- fallback (round-1) kernels: in-kernel f32->bf16 staging ----------------
__global__ __launch_bounds__(256) void k_gateup_f32(
    const float* __restrict__ x, const float* __restrict__ Wg, const float* __restrict__ Wu,
    const int* __restrict__ order, const int* __restrict__ tE, const int* __restrict__ tB,
    const int* __restrict__ tEnd, const int* __restrict__ nT, __bf16* __restrict__ hp) {
  const int tile = blockIdx.y;
  if (tile >= *nT) return;
  const int e = tE[tile];
  const int rowbase = tB[tile];
  const int rowEnd = tEnd[tile];
  const int nbase = blockIdx.x * BN;

  __shared__ __align__(16) unsigned char smA[BM * BK * 2];
  __shared__ __align__(16) unsigned char smG[BN * BK * 2];
  __shared__ __align__(16) unsigned char smU[BN * BK * 2];

  const int tid = threadIdx.x;
  const int lane = tid & 63;
  const int w = tid >> 6;
  const int wm = w >> 1, wn = w & 1;

  const int r = tid >> 1;
  const int c2 = tid & 1;
  const int gr_s = rowbase + r;
  const bool rvalid = gr_s < rowEnd;
  const float* xrow = rvalid ? (x + (size_t)order[gr_s] * H_DIM) : x;
  const float* grow = Wg + ((size_t)e * I_DIM + nbase + r) * H_DIM;
  const float* urow = Wu + ((size_t)e * I_DIM + nbase + r) * H_DIM;

  f32x4 accg[4][4], accu[4][4];
#pragma unroll
  for (int m = 0; m < 4; ++m)
#pragma unroll
    for (int n = 0; n < 4; ++n)
#pragma unroll
      for (int j = 0; j < 4; ++j) { accg[m][n][j] = 0.f; accu[m][n][j] = 0.f; }

  const int nK = H_DIM / BK;
  for (int kt = 0; kt < nK; ++kt) {
    const int kof = kt * BK + c2 * 32;
#pragma unroll
    for (int i = 0; i < 4; ++i) {
      const int off = SWZ(r, c2 * 64 + i * 16);
      if (rvalid) {
        const float4 p0 = *(const float4*)(xrow + kof + i * 8);
        const float4 p1 = *(const float4*)(xrow + kof + i * 8 + 4);
        cvt_store(smA, off, p0, p1);
      } else {
        bf16x8 z;
#pragma unroll
        for (int q = 0; q < 8; ++q) z[q] = (__bf16)0.f;
        *(bf16x8*)(smA + off) = z;
      }
    }
#pragma unroll
    for (int i = 0; i < 4; ++i) {
      const int off = SWZ(r, c2 * 64 + i * 16);
      const float4 g0 = *(const float4*)(grow + kof + i * 8);
      const float4 g1 = *(const float4*)(grow + kof + i * 8 + 4);
      cvt_store(smG, off, g0, g1);
      const float4 u0 = *(const float4*)(urow + kof + i * 8);
      const float4 u1 = *(const float4*)(urow + kof + i * 8 + 4);
      cvt_store(smU, off, u0, u1);
    }
    __syncthreads();
#pragma unroll
    for (int ks = 0; ks < 2; ++ks) {
      bf16x8 a[4], bg[4], bu[4];
#pragma unroll
      for (int m = 0; m < 4; ++m) {
        const int row = wm * 64 + m * 16 + (lane & 15);
        a[m] = *(const bf16x8*)(smA + SWZ(row, ks * 64 + ((lane >> 4) * 16)));
      }
#pragma unroll
      for (int n = 0; n < 4; ++n) {
        const int row = wn * 64 + n * 16 + (lane & 15);
        const int off = SWZ(row, ks * 64 + ((lane >> 4) * 16));
        bg[n] = *(const bf16x8*)(smG + off);
        bu[n] = *(const bf16x8*)(smU + off);
      }
#pragma unroll
      for (int m = 0; m < 4; ++m)
#pragma unroll
        for (int n = 0; n < 4; ++n) {
          accg[m][n] = __builtin_amdgcn_mfma_f32_16x16x32_bf16(a[m], bg[n], accg[m][n], 0, 0, 0);
          accu[m][n] = __builtin_amdgcn_mfma_f32_16x16x32_bf16(a[m], bu[n], accu[m][n], 0, 0, 0);
        }
    }
    __syncthreads();
  }

#pragma unroll
  for (int m = 0; m < 4; ++m) {
    const int row0 = wm * 64 + m * 16 + (lane >> 4) * 4;
#pragma unroll
    for (int j = 0; j < 4; ++j) {
      const int gr = rowbase + row0 + j;
      if (gr < rowEnd) {
        __bf16* dst = hp + (size_t)gr * I_DIM + nbase;
#pragma unroll
        for (int n = 0; n < 4; ++n) {
          const int col = wn * 64 + n * 16 + (lane & 15);
          const float g = accg[m][n][j];
          const float u = accu[m][n][j];
          dst[col] = (__bf16)(g / (1.f + __expf(-g)) * u);
        }
      }
    }
  }
}

__global__ __launch_bounds__(256) void k_down_f32(
    const __bf16* __restrict__ hp, const float* __restrict__ Wd,
    const int* __restrict__ order, const int* __restrict__ tE, const int* __restrict__ tB,
    const int* __restrict__ tEnd, const int* __restrict__ nT, float* __restrict__ out) {
  const int tile = blockIdx.y;
  if (tile >= *nT) return;
  const int e = tE[tile];
  const int rowbase = tB[tile];
  const int rowEnd = tEnd[tile];
  const int nbase = blockIdx.x * BN;

  __shared__ __align__(16) unsigned char smA[BM * BK * 2];
  __shared__ __align__(16) unsigned char smB[BN * BK * 2];

  const int tid = threadIdx.x;
  const int lane = tid & 63;
  const int w = tid >> 6;
  const int wm = w >> 1, wn = w & 1;

  const int r = tid >> 1;
  const int c2 = tid & 1;
  const __bf16* arow = hp + (size_t)(rowbase + r) * I_DIM;
  const float* brow = Wd + ((size_t)e * H_DIM + nbase + r) * I_DIM;

  f32x4 acc[4][4];
#pragma unroll
  for (int m = 0; m < 4; ++m)
#pragma unroll
    for (int n = 0; n < 4; ++n)
#pragma unroll
      for (int j = 0; j < 4; ++j) acc[m][n][j] = 0.f;

  const int nK = I_DIM / BK;
  for (int kt = 0; kt < nK; ++kt) {
#pragma unroll
    for (int i = 0; i < 4; ++i) {
      const bf16x8 v = *(const bf16x8*)(arow + kt * BK + c2 * 32 + i * 8);
      *(bf16x8*)(smA + SWZ(r, c2 * 64 + i * 16)) = v;
    }
    const int kof = kt * BK + c2 * 32;
#pragma unroll
    for (int i = 0; i < 4; ++i) {
      const float4 p0 = *(const float4*)(brow + kof + i * 8);
      const float4 p1 = *(const float4*)(brow + kof + i * 8 + 4);
      cvt_store(smB, SWZ(r, c2 * 64 + i * 16), p0, p1);
    }
    __syncthreads();
#pragma unroll
    for (int ks = 0; ks < 2; ++ks) {
      bf16x8 a[4], b[4];
#pragma unroll
      for (int m = 0; m < 4; ++m) {
        const int row = wm * 64 + m * 16 + (lane & 15);
        a[m] = *(const bf16x8*)(smA + SWZ(row, ks * 64 + ((lane >> 4) * 16)));
      }
#pragma unroll
      for (int n = 0; n < 4; ++n) {
        const int row = wn * 64 + n * 16 + (lane & 15);
        b[n] = *(const bf16x8*)(smB + SWZ(row, ks * 64 + ((lane >> 4) * 16)));
      }
#pragma unroll
      for (int m = 0; m < 4; ++m)
#pragma unroll
        for (int n = 0; n < 4; ++n)
          acc[m][n] = __builtin_amdgcn_mfma_f32_16x16x32_bf16(a[m], b[n], acc[m][n], 0, 0, 0);
    }
    __syncthreads();
  }

#pragma unroll
  for (int m = 0; m < 4; ++m) {
    const int row0 = wm * 64 + m * 16 + (lane >> 4) * 4;
#pragma unroll
    for (int j = 0; j < 4; ++j) {
      const int gr = rowbase + row0 + j;
      if (gr < rowEnd) {
        const int tok = order[gr];
        float* dst = out + (size_t)tok * H_DIM + nbase;
#pragma unroll
        for (int n = 0; n < 4; ++n) {
          const int col = wn * 64 + n * 16 + (lane & 15);
          dst[col] = acc[m][n][j];
        }
      }
    }
  }
}

// ---------------- launch ----------------
extern "C" void kernel_launch(void* const* d_in, const int* in_sizes, int n_in,
                              void* d_out, int out_size, void* d_ws, size_t ws_size,
                              hipStream_t stream) {
  const float* x = (const float*)d_in[0];
  const int* eidx = (const int*)d_in[1];
  const float* Wg = (const float*)d_in[2];
  const float* Wu = (const float*)d_in[3];
  const float* Wd = (const float*)d_in[4];
  float* out = (float*)d_out;

  char* ws = (char*)d_ws;
  size_t off = 0;
  auto alloc = [&](size_t bytes) -> void* {
    void* p = ws + off;
    off = (off + bytes + 255) & ~(size_t)255;
    return p;
  };
  const size_t TPAD = T_TOK + BM; // tile overreads stay within +128 rows
  __bf16* hp = (__bf16*)alloc(TPAD * I_DIM * sizeof(__bf16));
  int* order = (int*)alloc(T_TOK * sizeof(int));
  int* offsets = (int*)alloc((E_EXP + 1) * sizeof(int));
  int* tE = (int*)alloc(MAXTILES * sizeof(int));
  int* tB = (int*)alloc(MAXTILES * sizeof(int));
  int* tEnd = (int*)alloc(MAXTILES * sizeof(int));
  int* nT = (int*)alloc(sizeof(int));
  int* cc = (int*)alloc(2 * E_EXP * sizeof(int)); // counts | cursor
  int* counts = cc;
  int* cursor = cc + E_EXP;

  const size_t base_need = off;
  const size_t WSZ = (size_t)E_EXP * I_DIM * H_DIM; // elements per gate/up weight
  const size_t need_bf16 = base_need + (TPAD * H_DIM + 3 * WSZ) * sizeof(__bf16) + 1024;
  const bool use_bf16 = ws_size >= need_bf16;

  hipMemsetAsync(cc, 0, 2 * E_EXP * sizeof(int), stream);
  k_count<<<T_TOK / 256, 256, 0, stream>>>(eidx, counts);
  k_tiles<<<1, 1, 0, stream>>>(counts, offsets, tE, tB, tEnd, nT);
  k_scatter<<<T_TOK / 256, 256, 0, stream>>>(eidx, offsets, cursor, order);

  if (use_bf16) {
    __bf16* xp = (__bf16*)alloc(TPAD * H_DIM * sizeof(__bf16));
    __bf16* wg16 = (__bf16*)alloc(WSZ * sizeof(__bf16));
    __bf16* wu16 = (__bf16*)alloc(WSZ * sizeof(__bf16));
    __bf16* wd16 = (__bf16*)alloc(WSZ * sizeof(__bf16));
    const int n8 = (int)(WSZ / 8);
    k_cvt<<<(n8 + 255) / 256, 256, 0, stream>>>(Wg, wg16, n8);
    k_cvt<<<(n8 + 255) / 256, 256, 0, stream>>>(Wu, wu16, n8);
    k_cvt<<<(n8 + 255) / 256, 256, 0, stream>>>(Wd, wd16, n8);
    k_xperm<<<T_TOK, 128, 0, stream>>>(x, order, xp);
    k_gateup2<<<dim3(I_DIM / BN, MAXTILES), 256, 0, stream>>>(xp, wg16, wu16, tE, tB, tEnd, nT, hp);
    k_down2<<<dim3(H_DIM / BN, MAXTILES), 256, 0, stream>>>(hp, wd16, order, tE, tB, tEnd, nT, out);
  } else {
    k_gateup_f32<<<dim3(I_DIM / BN, MAXTILES), 256, 0, stream>>>(x, Wg, Wu, order, tE, tB, tEnd, nT, hp);
    k_down_f32<<<dim3(H_DIM / BN, MAXTILES), 256, 0, stream>>>(hp, Wd, order, tE, tB, tEnd, nT, out);
  }
}

// Round 3
// 386.604 us; speedup vs baseline: 1.9161x; 1.1416x over previous
//
#include <hip/hip_runtime.h>
#include <hip/hip_bf16.h>

// Problem constants (reference: T=8192, H=1024, I=2816, E=8)
#define T_TOK 8192
#define H_DIM 1024
#define I_DIM 2816
#define E_EXP 8

#define BM 128
#define BN 128
#define BK 64
#define MAXTILES (T_TOK / BM + E_EXP) // 72 worst case

typedef __bf16 bf16x8 __attribute__((ext_vector_type(8)));
typedef float f32x4 __attribute__((ext_vector_type(4)));

// swizzled LDS byte offset for a [rows][BK(bf16)] tile; row stride = BK*2 = 128B
#define SWZ(r, bc) (((r) * (BK * 2)) + (((bc) ^ (((r) & 7) << 4))))

__device__ __forceinline__ void gload16(const void* g, void* l) {
  __builtin_amdgcn_global_load_lds((const __attribute__((address_space(1))) void*)g,
                                   (__attribute__((address_space(3))) void*)l, 16, 0, 0);
}

__device__ __forceinline__ bf16x8 cvt8(const float4& p0, const float4& p1) {
  bf16x8 v;
  v[0] = (__bf16)p0.x; v[1] = (__bf16)p0.y; v[2] = (__bf16)p0.z; v[3] = (__bf16)p0.w;
  v[4] = (__bf16)p1.x; v[5] = (__bf16)p1.y; v[6] = (__bf16)p1.z; v[7] = (__bf16)p1.w;
  return v;
}

// ---------------- bucketing kernels ----------------
__global__ void k_count(const int* __restrict__ idx, int* __restrict__ counts) {
  int t = blockIdx.x * blockDim.x + threadIdx.x;
  if (t < T_TOK) atomicAdd(&counts[idx[t]], 1);
}

__global__ void k_tiles(const int* __restrict__ counts, int* __restrict__ offsets,
                        int* __restrict__ tE, int* __restrict__ tB,
                        int* __restrict__ tEnd, int* __restrict__ nT) {
  if (threadIdx.x != 0 || blockIdx.x != 0) return;
  int off = 0, nt = 0;
  for (int e = 0; e < E_EXP; ++e) {
    offsets[e] = off;
    int c = counts[e];
    for (int b = 0; b < c; b += BM) { tE[nt] = e; tB[nt] = off + b; tEnd[nt] = off + c; ++nt; }
    off += c;
  }
  offsets[E_EXP] = off;
  *nT = nt;
}

__global__ void k_scatter(const int* __restrict__ idx, const int* __restrict__ offsets,
                          int* __restrict__ cursor, int* __restrict__ order) {
  int t = blockIdx.x * blockDim.x + threadIdx.x;
  if (t < T_TOK) {
    int e = idx[t];
    int p = offsets[e] + atomicAdd(&cursor[e], 1);
    order[p] = t;
  }
}

// ---------------- bf16 pre-conversion ----------------
__global__ __launch_bounds__(256) void k_cvt(const float* __restrict__ src,
                                             __bf16* __restrict__ dst, int n8) {
  int i = blockIdx.x * blockDim.x + threadIdx.x;
  if (i < n8) {
    const float4 p0 = ((const float4*)src)[i * 2];
    const float4 p1 = ((const float4*)src)[i * 2 + 1];
    ((bf16x8*)dst)[i] = cvt8(p0, p1);
  }
}

// gather by order + convert x -> xp (bf16, permuted rows)
__global__ __launch_bounds__(128) void k_xperm(const float* __restrict__ x,
                                               const int* __restrict__ order,
                                               __bf16* __restrict__ xp) {
  const int row = blockIdx.x;
  const int tok = order[row];
  const float* s = x + (size_t)tok * H_DIM + threadIdx.x * 8;
  const float4 p0 = ((const float4*)s)[0];
  const float4 p1 = ((const float4*)s)[1];
  *(bf16x8*)(xp + (size_t)row * H_DIM + threadIdx.x * 8) = cvt8(p0, p1);
}

// =====================================================================
// pass 2 (8-wave, prefetch double-buffered): gate/up GEMM + silu*mul -> hp
// dynamic LDS: 3 operands x 2 buffers x 16KB = 96KB, 1 block/CU
// =====================================================================
__global__ __launch_bounds__(512, 2) void k_gateup3(
    const __bf16* __restrict__ xp, const __bf16* __restrict__ wg, const __bf16* __restrict__ wu,
    const int* __restrict__ tE, const int* __restrict__ tB,
    const int* __restrict__ tEnd, const int* __restrict__ nT, __bf16* __restrict__ hp) {
  const int tile = blockIdx.y;
  if (tile >= *nT) return;
  const int e = tE[tile];
  const int rowbase = tB[tile];
  const int rowEnd = tEnd[tile];
  const int nbase = blockIdx.x * BN;

  extern __shared__ __align__(16) unsigned char smem[];
  unsigned char* smA = smem;          // [2][16384]
  unsigned char* smG = smem + 32768;  // [2][16384]
  unsigned char* smU = smem + 65536;  // [2][16384]

  const int tid = threadIdx.x;
  const int lane = tid & 63;
  const int w = tid >> 6;            // 0..7
  const int wm = w & 1, wn = w >> 1; // wave tile = 64 rows x 32 cols

  // staging: 2 rounds of 64 rows; lane -> row (lane>>3), pre-swizzled chunk
  const int lr = lane >> 3;
  const int lc = (lane & 7) ^ lr;
  const __bf16* aS[2]; const __bf16* gS[2]; const __bf16* uS[2];
  int ldst[2];
#pragma unroll
  for (int r = 0; r < 2; ++r) {
    const int rt = r * 64 + w * 8 + lr;
    aS[r] = xp + (size_t)(rowbase + rt) * H_DIM + lc * 8;
    gS[r] = wg + ((size_t)e * I_DIM + nbase + rt) * H_DIM + lc * 8;
    uS[r] = wu + ((size_t)e * I_DIM + nbase + rt) * H_DIM + lc * 8;
    ldst[r] = (r * 64 + w * 8) * 128;
  }

  f32x4 accg[4][2], accu[4][2];
#pragma unroll
  for (int m = 0; m < 4; ++m)
#pragma unroll
    for (int n = 0; n < 2; ++n)
#pragma unroll
      for (int j = 0; j < 4; ++j) { accg[m][n][j] = 0.f; accu[m][n][j] = 0.f; }

  const int nK = H_DIM / BK; // 16
  // prologue: stage tile 0 into buffer 0
#pragma unroll
  for (int r = 0; r < 2; ++r) {
    gload16(aS[r], smA + ldst[r]);
    gload16(gS[r], smG + ldst[r]);
    gload16(uS[r], smU + ldst[r]);
  }
  __syncthreads();

  int cur = 0;
  for (int kt = 0; kt < nK; ++kt) {
    // issue next-tile loads into the other buffer (hidden under MFMA below)
    if (kt + 1 < nK) {
      const int kof = (kt + 1) * BK;
      const int b = (cur ^ 1) * 16384;
#pragma unroll
      for (int r = 0; r < 2; ++r) {
        gload16(aS[r] + kof, smA + b + ldst[r]);
        gload16(gS[r] + kof, smG + b + ldst[r]);
        gload16(uS[r] + kof, smU + b + ldst[r]);
      }
    }
    const unsigned char* A = smA + cur * 16384;
    const unsigned char* G = smG + cur * 16384;
    const unsigned char* U = smU + cur * 16384;
#pragma unroll
    for (int ks = 0; ks < 2; ++ks) {
      bf16x8 a[4], bg[2], bu[2];
#pragma unroll
      for (int m = 0; m < 4; ++m) {
        const int row = wm * 64 + m * 16 + (lane & 15);
        a[m] = *(const bf16x8*)(A + SWZ(row, ks * 64 + ((lane >> 4) * 16)));
      }
#pragma unroll
      for (int n = 0; n < 2; ++n) {
        const int row = wn * 32 + n * 16 + (lane & 15);
        const int off = SWZ(row, ks * 64 + ((lane >> 4) * 16));
        bg[n] = *(const bf16x8*)(G + off);
        bu[n] = *(const bf16x8*)(U + off);
      }
#pragma unroll
      for (int m = 0; m < 4; ++m)
#pragma unroll
        for (int n = 0; n < 2; ++n) {
          accg[m][n] = __builtin_amdgcn_mfma_f32_16x16x32_bf16(a[m], bg[n], accg[m][n], 0, 0, 0);
          accu[m][n] = __builtin_amdgcn_mfma_f32_16x16x32_bf16(a[m], bu[n], accu[m][n], 0, 0, 0);
        }
    }
    __syncthreads(); // drains prefetch (vmcnt) + protects cur buffer reuse
    cur ^= 1;
  }

  // epilogue: h = silu(g)*u -> hp (bf16, permuted row layout)
#pragma unroll
  for (int m = 0; m < 4; ++m) {
    const int row0 = wm * 64 + m * 16 + (lane >> 4) * 4;
#pragma unroll
    for (int j = 0; j < 4; ++j) {
      const int gr = rowbase + row0 + j;
      if (gr < rowEnd) {
        __bf16* dst = hp + (size_t)gr * I_DIM + nbase;
#pragma unroll
        for (int n = 0; n < 2; ++n) {
          const int col = wn * 32 + n * 16 + (lane & 15);
          const float g = accg[m][n][j];
          const float u = accu[m][n][j];
          dst[col] = (__bf16)(g / (1.f + __expf(-g)) * u);
        }
      }
    }
  }
}

// =====================================================================
// pass 3 (8-wave, prefetch double-buffered): down GEMM, scatter rows to out
// dynamic LDS: 2 operands x 2 buffers x 16KB = 64KB, 2 blocks/CU
// =====================================================================
__global__ __launch_bounds__(512, 2) void k_down3(
    const __bf16* __restrict__ hp, const __bf16* __restrict__ wd,
    const int* __restrict__ order, const int* __restrict__ tE, const int* __restrict__ tB,
    const int* __restrict__ tEnd, const int* __restrict__ nT, float* __restrict__ out) {
  const int tile = blockIdx.y;
  if (tile >= *nT) return;
  const int e = tE[tile];
  const int rowbase = tB[tile];
  const int rowEnd = tEnd[tile];
  const int nbase = blockIdx.x * BN; // over H

  extern __shared__ __align__(16) unsigned char smem2[];
  unsigned char* smA = smem2;          // [2][16384]
  unsigned char* smB = smem2 + 32768;  // [2][16384]

  const int tid = threadIdx.x;
  const int lane = tid & 63;
  const int w = tid >> 6;
  const int wm = w & 1, wn = w >> 1; // wave tile = 64 x 32

  const int lr = lane >> 3;
  const int lc = (lane & 7) ^ lr;
  const __bf16* aS[2]; const __bf16* bS[2];
  int ldst[2];
#pragma unroll
  for (int r = 0; r < 2; ++r) {
    const int rt = r * 64 + w * 8 + lr;
    aS[r] = hp + (size_t)(rowbase + rt) * I_DIM + lc * 8;
    bS[r] = wd + ((size_t)e * H_DIM + nbase + rt) * I_DIM + lc * 8;
    ldst[r] = (r * 64 + w * 8) * 128;
  }

  f32x4 acc[4][2];
#pragma unroll
  for (int m = 0; m < 4; ++m)
#pragma unroll
    for (int n = 0; n < 2; ++n)
#pragma unroll
      for (int j = 0; j < 4; ++j) acc[m][n][j] = 0.f;

  const int nK = I_DIM / BK; // 44
#pragma unroll
  for (int r = 0; r < 2; ++r) {
    gload16(aS[r], smA + ldst[r]);
    gload16(bS[r], smB + ldst[r]);
  }
  __syncthreads();

  int cur = 0;
  for (int kt = 0; kt < nK; ++kt) {
    if (kt + 1 < nK) {
      const int kof = (kt + 1) * BK;
      const int b = (cur ^ 1) * 16384;
#pragma unroll
      for (int r = 0; r < 2; ++r) {
        gload16(aS[r] + kof, smA + b + ldst[r]);
        gload16(bS[r] + kof, smB + b + ldst[r]);
      }
    }
    const unsigned char* A = smA + cur * 16384;
    const unsigned char* B = smB + cur * 16384;
#pragma unroll
    for (int ks = 0; ks < 2; ++ks) {
      bf16x8 a[4], b[2];
#pragma unroll
      for (int m = 0; m < 4; ++m) {
        const int row = wm * 64 + m * 16 + (lane & 15);
        a[m] = *(const bf16x8*)(A + SWZ(row, ks * 64 + ((lane >> 4) * 16)));
      }
#pragma unroll
      for (int n = 0; n < 2; ++n) {
        const int row = wn * 32 + n * 16 + (lane & 15);
        b[n] = *(const bf16x8*)(B + SWZ(row, ks * 64 + ((lane >> 4) * 16)));
      }
#pragma unroll
      for (int m = 0; m < 4; ++m)
#pragma unroll
        for (int n = 0; n < 2; ++n)
          acc[m][n] = __builtin_amdgcn_mfma_f32_16x16x32_bf16(a[m], b[n], acc[m][n], 0, 0, 0);
    }
    __syncthreads();
    cur ^= 1;
  }

#pragma unroll
  for (int m = 0; m < 4; ++m) {
    const int row0 = wm * 64 + m * 16 + (lane >> 4) * 4;
#pragma unroll
    for (int j = 0; j < 4; ++j) {
      const int gr = rowbase + row0 + j;
      if (gr < rowEnd) {
        const int tok = order[gr];
        float* dst = out + (size_t)tok * H_DIM + nbase;
#pragma unroll
        for (int n = 0; n < 2; ++n) {
          const int col = wn * 32 + n * 16 + (lane & 15);
          dst[col] = acc[m][n][j];
        }
      }
    }
  }
}

// ---------------- fallback (round-2, static 48KB LDS) kernels ----------------
__global__ __launch_bounds__(256) void k_gateup2(
    const __bf16* __restrict__ xp, const __bf16* __restrict__ wg, const __bf16* __restrict__ wu,
    const int* __restrict__ tE, const int* __restrict__ tB,
    const int* __restrict__ tEnd, const int* __restrict__ nT, __bf16* __restrict__ hp) {
  const int tile = blockIdx.y;
  if (tile >= *nT) return;
  const int e = tE[tile];
  const int rowbase = tB[tile];
  const int rowEnd = tEnd[tile];
  const int nbase = blockIdx.x * BN;

  __shared__ __align__(16) unsigned char smA[BM * BK * 2];
  __shared__ __align__(16) unsigned char smG[BN * BK * 2];
  __shared__ __align__(16) unsigned char smU[BN * BK * 2];

  const int tid = threadIdx.x;
  const int lane = tid & 63;
  const int w = tid >> 6;
  const int wm = w >> 1, wn = w & 1;

  const int lrow = lane >> 3;
  const int lchunk = (lane & 7) ^ lrow;
  const __bf16* aptr[4];
  const __bf16* gptr[4];
  const __bf16* uptr[4];
#pragma unroll
  for (int j = 0; j < 4; ++j) {
    const int rl = (w * 4 + j) * 8 + lrow;
    aptr[j] = xp + (size_t)(rowbase + rl) * H_DIM + lchunk * 8;
    gptr[j] = wg + ((size_t)e * I_DIM + nbase + rl) * H_DIM + lchunk * 8;
    uptr[j] = wu + ((size_t)e * I_DIM + nbase + rl) * H_DIM + lchunk * 8;
  }

  f32x4 accg[4][4], accu[4][4];
#pragma unroll
  for (int m = 0; m < 4; ++m)
#pragma unroll
    for (int n = 0; n < 4; ++n)
#pragma unroll
      for (int j = 0; j < 4; ++j) { accg[m][n][j] = 0.f; accu[m][n][j] = 0.f; }

  const int nK = H_DIM / BK;
  for (int kt = 0; kt < nK; ++kt) {
    const int kof = kt * BK;
#pragma unroll
    for (int j = 0; j < 4; ++j) {
      gload16(aptr[j] + kof, (unsigned char*)smA + (w * 4 + j) * 1024);
      gload16(gptr[j] + kof, (unsigned char*)smG + (w * 4 + j) * 1024);
      gload16(uptr[j] + kof, (unsigned char*)smU + (w * 4 + j) * 1024);
    }
    __syncthreads();
#pragma unroll
    for (int ks = 0; ks < 2; ++ks) {
      bf16x8 a[4], bg[4], bu[4];
#pragma unroll
      for (int m = 0; m < 4; ++m) {
        const int row = wm * 64 + m * 16 + (lane & 15);
        a[m] = *(const bf16x8*)(smA + SWZ(row, ks * 64 + ((lane >> 4) * 16)));
      }
#pragma unroll
      for (int n = 0; n < 4; ++n) {
        const int row = wn * 64 + n * 16 + (lane & 15);
        const int off = SWZ(row, ks * 64 + ((lane >> 4) * 16));
        bg[n] = *(const bf16x8*)(smG + off);
        bu[n] = *(const bf16x8*)(smU + off);
      }
#pragma unroll
      for (int m = 0; m < 4; ++m)
#pragma unroll
        for (int n = 0; n < 4; ++n) {
          accg[m][n] = __builtin_amdgcn_mfma_f32_16x16x32_bf16(a[m], bg[n], accg[m][n], 0, 0, 0);
          accu[m][n] = __builtin_amdgcn_mfma_f32_16x16x32_bf16(a[m], bu[n], accu[m][n], 0, 0, 0);
        }
    }
    __syncthreads();
  }

#pragma unroll
  for (int m = 0; m < 4; ++m) {
    const int row0 = wm * 64 + m * 16 + (lane >> 4) * 4;
#pragma unroll
    for (int j = 0; j < 4; ++j) {
      const int gr = rowbase + row0 + j;
      if (gr < rowEnd) {
        __bf16* dst = hp + (size_t)gr * I_DIM + nbase;
#pragma unroll
        for (int n = 0; n < 4; ++n) {
          const int col = wn * 64 + n * 16 + (lane & 15);
          const float g = accg[m][n][j];
          const float u = accu[m][n][j];
          dst[col] = (__bf16)(g / (1.f + __expf(-g)) * u);
        }
      }
    }
  }
}

__global__ __launch_bounds__(256) void k_down2(
    const __bf16* __restrict__ hp, const __bf16* __restrict__ wd,
    const int* __restrict__ order, const int* __restrict__ tE, const int* __restrict__ tB,
    const int* __restrict__ tEnd, const int* __restrict__ nT, float* __restrict__ out) {
  const int tile = blockIdx.y;
  if (tile >= *nT) return;
  const int e = tE[tile];
  const int rowbase = tB[tile];
  const int rowEnd = tEnd[tile];
  const int nbase = blockIdx.x * BN;

  __shared__ __align__(16) unsigned char smA[BM * BK * 2];
  __shared__ __align__(16) unsigned char smB[BN * BK * 2];

  const int tid = threadIdx.x;
  const int lane = tid & 63;
  const int w = tid >> 6;
  const int wm = w >> 1, wn = w & 1;

  const int lrow = lane >> 3;
  const int lchunk = (lane & 7) ^ lrow;
  const __bf16* aptr[4];
  const __bf16* bptr[4];
#pragma unroll
  for (int j = 0; j < 4; ++j) {
    const int rl = (w * 4 + j) * 8 + lrow;
    aptr[j] = hp + (size_t)(rowbase + rl) * I_DIM + lchunk * 8;
    bptr[j] = wd + ((size_t)e * H_DIM + nbase + rl) * I_DIM + lchunk * 8;
  }

  f32x4 acc[4][4];
#pragma unroll
  for (int m = 0; m < 4; ++m)
#pragma unroll
    for (int n = 0; n < 4; ++n)
#pragma unroll
      for (int j = 0; j < 4; ++j) acc[m][n][j] = 0.f;

  const int nK = I_DIM / BK;
  for (int kt = 0; kt < nK; ++kt) {
    const int kof = kt * BK;
#pragma unroll
    for (int j = 0; j < 4; ++j) {
      gload16(aptr[j] + kof, (unsigned char*)smA + (w * 4 + j) * 1024);
      gload16(bptr[j] + kof, (unsigned char*)smB + (w * 4 + j) * 1024);
    }
    __syncthreads();
#pragma unroll
    for (int ks = 0; ks < 2; ++ks) {
      bf16x8 a[4], b[4];
#pragma unroll
      for (int m = 0; m < 4; ++m) {
        const int row = wm * 64 + m * 16 + (lane & 15);
        a[m] = *(const bf16x8*)(smA + SWZ(row, ks * 64 + ((lane >> 4) * 16)));
      }
#pragma unroll
      for (int n = 0; n < 4; ++n) {
        const int row = wn * 64 + n * 16 + (lane & 15);
        b[n] = *(const bf16x8*)(smB + SWZ(row, ks * 64 + ((lane >> 4) * 16)));
      }
#pragma unroll
      for (int m = 0; m < 4; ++m)
#pragma unroll
        for (int n = 0; n < 4; ++n)
          acc[m][n] = __builtin_amdgcn_mfma_f32_16x16x32_bf16(a[m], b[n], acc[m][n], 0, 0, 0);
    }
    __syncthreads();
  }

#pragma unroll
  for (int m = 0; m < 4; ++m) {
    const int row0 = wm * 64 + m * 16 + (lane >> 4) * 4;
#pragma unroll
    for (int j = 0; j < 4; ++j) {
      const int gr = rowbase + row0 + j;
      if (gr < rowEnd) {
        const int tok = order[gr];
        float* dst = out + (size_t)tok * H_DIM + nbase;
#pragma unroll
        for (int n = 0; n < 4; ++n) {
          const int col = wn * 64 + n * 16 + (lane & 15);
          dst[col] = acc[m][n][j];
        }
      }
    }
  }
}

// ---------------- launch ----------------
extern "C" void kernel_launch(void* const* d_in, const int* in_sizes, int n_in,
                              void* d_out, int out_size, void* d_ws, size_t ws_size,
                              hipStream_t stream) {
  const float* x = (const float*)d_in[0];
  const int* eidx = (const int*)d_in[1];
  const float* Wg = (const float*)d_in[2];
  const float* Wu = (const float*)d_in[3];
  const float* Wd = (const float*)d_in[4];
  float* out = (float*)d_out;

  char* ws = (char*)d_ws;
  size_t off = 0;
  auto alloc = [&](size_t bytes) -> void* {
    void* p = ws + off;
    off = (off + bytes + 255) & ~(size_t)255;
    return p;
  };
  const size_t TPAD = T_TOK + BM; // tile overreads stay within +128 rows
  __bf16* hp = (__bf16*)alloc(TPAD * I_DIM * sizeof(__bf16));
  int* order = (int*)alloc(T_TOK * sizeof(int));
  int* offsets = (int*)alloc((E_EXP + 1) * sizeof(int));
  int* tE = (int*)alloc(MAXTILES * sizeof(int));
  int* tB = (int*)alloc(MAXTILES * sizeof(int));
  int* tEnd = (int*)alloc(MAXTILES * sizeof(int));
  int* nT = (int*)alloc(sizeof(int));
  int* cc = (int*)alloc(2 * E_EXP * sizeof(int)); // counts | cursor
  int* counts = cc;
  int* cursor = cc + E_EXP;

  const size_t WSZ = (size_t)E_EXP * I_DIM * H_DIM; // elements per weight tensor
  __bf16* xp = (__bf16*)alloc(TPAD * H_DIM * sizeof(__bf16));
  __bf16* wg16 = (__bf16*)alloc(WSZ * sizeof(__bf16));
  __bf16* wu16 = (__bf16*)alloc(WSZ * sizeof(__bf16));
  __bf16* wd16 = (__bf16*)alloc(WSZ * sizeof(__bf16));

  // opt in to >64KB dynamic LDS (not a stream op; safe under graph capture)
  bool big_lds = true;
  big_lds &= hipFuncSetAttribute((const void*)k_gateup3,
                                 hipFuncAttributeMaxDynamicSharedMemorySize, 98304) == hipSuccess;
  big_lds &= hipFuncSetAttribute((const void*)k_down3,
                                 hipFuncAttributeMaxDynamicSharedMemorySize, 65536) == hipSuccess;

  hipMemsetAsync(cc, 0, 2 * E_EXP * sizeof(int), stream);
  k_count<<<T_TOK / 256, 256, 0, stream>>>(eidx, counts);
  k_tiles<<<1, 1, 0, stream>>>(counts, offsets, tE, tB, tEnd, nT);
  k_scatter<<<T_TOK / 256, 256, 0, stream>>>(eidx, offsets, cursor, order);

  const int n8 = (int)(WSZ / 8);
  k_cvt<<<(n8 + 255) / 256, 256, 0, stream>>>(Wg, wg16, n8);
  k_cvt<<<(n8 + 255) / 256, 256, 0, stream>>>(Wu, wu16, n8);
  k_cvt<<<(n8 + 255) / 256, 256, 0, stream>>>(Wd, wd16, n8);
  k_xperm<<<T_TOK, 128, 0, stream>>>(x, order, xp);

  if (big_lds) {
    k_gateup3<<<dim3(I_DIM / BN, MAXTILES), 512, 98304, stream>>>(xp, wg16, wu16, tE, tB, tEnd, nT, hp);
    k_down3<<<dim3(H_DIM / BN, MAXTILES), 512, 65536, stream>>>(hp, wd16, order, tE, tB, tEnd, nT, out);
  } else {
    k_gateup2<<<dim3(I_DIM / BN, MAXTILES), 256, 0, stream>>>(xp, wg16, wu16, tE, tB, tEnd, nT, hp);
    k_down2<<<dim3(H_DIM / BN, MAXTILES), 256, 0, stream>>>(hp, wd16, order, tE, tB, tEnd, nT, out);
  }
}